// Round 5
// baseline (557.907 us; speedup 1.0000x reference)
//
#include <hip/hip_runtime.h>

#define ED 2048
#define MR 8192

typedef unsigned short u16;
typedef __attribute__((ext_vector_type(8))) __bf16 bf16x8;
typedef __attribute__((ext_vector_type(4))) float f32x4;

__device__ __forceinline__ u16 f2bf(float f){ __bf16 h=(__bf16)f; return __builtin_bit_cast(u16,h); }
__device__ __forceinline__ float bf2f(u16 u){ __bf16 h=__builtin_bit_cast(__bf16,u); return (float)h; }

#define MFMA __builtin_amdgcn_mfma_f32_16x16x32_bf16

// async global->LDS, 16B per lane; LDS dest is wave-uniform base + lane*16
#define LDSLOAD(gp, lp) __builtin_amdgcn_global_load_lds( \
    (const __attribute__((address_space(1))) unsigned int*)(gp), \
    (__attribute__((address_space(3))) unsigned int*)(lp), 16, 0, 0)

// ---------------------------------------------------------------------------
// split fp32 -> hi/lo bf16 (elementwise, float4 vectorized, grid-stride)
// ---------------------------------------------------------------------------
__global__ void split_kernel(const float* __restrict__ in, u16* __restrict__ hi,
                             u16* __restrict__ lo, int n4) {
    int i = blockIdx.x * 256 + threadIdx.x;
    const int stride = gridDim.x * 256;
    for (; i < n4; i += stride) {
        float4 v = reinterpret_cast<const float4*>(in)[i];
        ushort4 h, l;
        h.x = f2bf(v.x); l.x = f2bf(v.x - bf2f(h.x));
        h.y = f2bf(v.y); l.y = f2bf(v.y - bf2f(h.y));
        h.z = f2bf(v.z); l.z = f2bf(v.z - bf2f(h.z));
        h.w = f2bf(v.w); l.w = f2bf(v.w - bf2f(h.w));
        reinterpret_cast<ushort4*>(hi)[i] = h;
        reinterpret_cast<ushort4*>(lo)[i] = l;
    }
}

// ---------------------------------------------------------------------------
// hi/lo = split(a + b)  — split-K slab reduction
// ---------------------------------------------------------------------------
__global__ void reduce2_split(const float* __restrict__ a, const float* __restrict__ b,
                              u16* __restrict__ hi, u16* __restrict__ lo, int n4) {
    int i = blockIdx.x * 256 + threadIdx.x;
    const int stride = gridDim.x * 256;
    for (; i < n4; i += stride) {
        float4 va = reinterpret_cast<const float4*>(a)[i];
        float4 vb = reinterpret_cast<const float4*>(b)[i];
        float4 v; v.x = va.x + vb.x; v.y = va.y + vb.y; v.z = va.z + vb.z; v.w = va.w + vb.w;
        ushort4 h, l;
        h.x = f2bf(v.x); l.x = f2bf(v.x - bf2f(h.x));
        h.y = f2bf(v.y); l.y = f2bf(v.y - bf2f(h.y));
        h.z = f2bf(v.z); l.z = f2bf(v.z - bf2f(h.z));
        h.w = f2bf(v.w); l.w = f2bf(v.w - bf2f(h.w));
        reinterpret_cast<ushort4*>(hi)[i] = h;
        reinterpret_cast<ushort4*>(lo)[i] = l;
    }
}

// ---------------------------------------------------------------------------
// 32x32 tiled transpose fp32 -> fp32 (minimal path)
// ---------------------------------------------------------------------------
__global__ void transpose_f32(const float* __restrict__ in, float* __restrict__ out, int n) {
    __shared__ float tile[32][33];
    const int bx = blockIdx.x * 32, by = blockIdx.y * 32;
    const int tx = threadIdx.x & 31, ty = threadIdx.x >> 5;
    #pragma unroll
    for (int r = ty; r < 32; r += 8)
        tile[r][tx] = in[(size_t)(by + r) * n + bx + tx];
    __syncthreads();
    #pragma unroll
    for (int r = ty; r < 32; r += 8)
        out[(size_t)(bx + r) * n + by + tx] = tile[tx][r];
}

// ---------------------------------------------------------------------------
// 32x32 tiled transpose fp32 -> hi/lo bf16
// ---------------------------------------------------------------------------
__global__ void transpose_split(const float* __restrict__ in, u16* __restrict__ hi,
                                u16* __restrict__ lo, int n) {
    __shared__ float tile[32][33];
    const int bx = blockIdx.x * 32, by = blockIdx.y * 32;
    const int tx = threadIdx.x & 31, ty = threadIdx.x >> 5;
    #pragma unroll
    for (int r = ty; r < 32; r += 8)
        tile[r][tx] = in[(size_t)(by + r) * n + bx + tx];
    __syncthreads();
    #pragma unroll
    for (int r = ty; r < 32; r += 8) {
        float v = tile[tx][r];
        u16 h = f2bf(v);
        size_t o = (size_t)(bx + r) * n + by + tx;
        hi[o] = h;
        lo[o] = f2bf(v - bf2f(h));
    }
}

// ---------------------------------------------------------------------------
// bp[n] += (bc[n] if first chunk) + sum_{j chunk of 64} bv[j]*Wc[j][n]
// ---------------------------------------------------------------------------
__global__ void bias_kernel(const float* __restrict__ bv, const float* __restrict__ Wc,
                            const float* __restrict__ bc, float* __restrict__ bp) {
    const int n = blockIdx.x * 256 + threadIdx.x;
    const int j0 = blockIdx.y * 64;
    float s = (blockIdx.y == 0) ? bc[n] : 0.0f;
    #pragma unroll 4
    for (int j = 0; j < 64; ++j)
        s += bv[j0 + j] * Wc[(size_t)(j0 + j) * ED + n];
    atomicAdd(&bp[n], s);
}

// ===========================================================================
// MAIN GEMM: 256x256, BK=32, 8 waves (2x4), dbuf LDS 128KB, counted vmcnt(8),
// 4-phase compute (T3/T4/T5): per phase {4 ds_read, lgkm(0), setprio(1),
// 24 MFMA, setprio(0), s_barrier}. B-frags register-held from phase 0.
// LDS slot-major per plane (256x32 bf16): elem (r,k) at (k>>3)*2048 + r*8 + (k&7).
// ===========================================================================
__global__ __launch_bounds__(512, 1)
void gemm256(const u16* __restrict__ Ahi, const u16* __restrict__ Alo,
             const u16* __restrict__ Bhi, const u16* __restrict__ Blo,
             float* __restrict__ Cout, const float* __restrict__ bias,
             int Kd, int Nd)
{
    __shared__ __align__(16) u16 sAhi[2][8192];
    __shared__ __align__(16) u16 sAlo[2][8192];
    __shared__ __align__(16) u16 sBhi[2][8192];
    __shared__ __align__(16) u16 sBlo[2][8192];

    const int tid = threadIdx.x, lane = tid & 63, wave = tid >> 6;
    const int wm = wave >> 2, wn = wave & 3;          // 2 x 4 wave grid
    const int lrow = lane & 15, kq = lane >> 4;

    // XCD-chunked bijective swizzle (nwg = 256, %8 == 0)
    const int nwg = gridDim.x * gridDim.y;
    const int lin = blockIdx.y * gridDim.x + blockIdx.x;
    const int lin2 = (lin & 7) * (nwg >> 3) + (lin >> 3);
    const int bx = lin2 % gridDim.x, by = lin2 / gridDim.x;
    const long m0 = (long)bx * 256;
    const long n0 = (long)by * 256;

    // staging: 16 16B-chunk-calls per plane; wave handles c0=wave*2, c1=c0+1.
    // call c: k-slot c>>2, rows (c&3)*64 + lane, LDS elem base c*512.
    const int c0 = wave * 2, c1 = c0 + 1;
    const int lb0 = c0 * 512, lb1 = c1 * 512;
    const long ga0 = (m0 + (c0 & 3) * 64 + lane) * (long)Kd + (c0 >> 2) * 8;
    const long ga1 = (m0 + (c1 & 3) * 64 + lane) * (long)Kd + (c1 >> 2) * 8;
    const long gb0 = (n0 + (c0 & 3) * 64 + lane) * (long)Kd + (c0 >> 2) * 8;
    const long gb1 = (n0 + (c1 & 3) * 64 + lane) * (long)Kd + (c1 >> 2) * 8;

    f32x4 acc[8][4];
    #pragma unroll
    for (int i = 0; i < 8; ++i)
        #pragma unroll
        for (int j = 0; j < 4; ++j)
            acc[i][j] = (f32x4){0.f, 0.f, 0.f, 0.f};

#define STAGE(buf, kt) do { \
    LDSLOAD(Ahi + ga0 + (kt), &sAhi[buf][lb0]); \
    LDSLOAD(Ahi + ga1 + (kt), &sAhi[buf][lb1]); \
    LDSLOAD(Alo + ga0 + (kt), &sAlo[buf][lb0]); \
    LDSLOAD(Alo + ga1 + (kt), &sAlo[buf][lb1]); \
    LDSLOAD(Bhi + gb0 + (kt), &sBhi[buf][lb0]); \
    LDSLOAD(Bhi + gb1 + (kt), &sBhi[buf][lb1]); \
    LDSLOAD(Blo + gb0 + (kt), &sBlo[buf][lb0]); \
    LDSLOAD(Blo + gb1 + (kt), &sBlo[buf][lb1]); \
} while (0)

    const int NT = Kd >> 5;   // 64
    STAGE(0, 0);

    for (int t = 0; t < NT; ++t) {
        const int cur = t & 1;
        if (t + 1 < NT) {
            STAGE(cur ^ 1, (t + 1) << 5);
            asm volatile("s_waitcnt vmcnt(8)" ::: "memory");   // stage(t) done, stage(t+1) flying
        } else {
            asm volatile("s_waitcnt vmcnt(0)" ::: "memory");
        }
        __builtin_amdgcn_s_barrier();       // buf[cur] ready on all waves
        __builtin_amdgcn_sched_barrier(0);

        // phase 0 preamble: B fragments (register-held across all phases)
        bf16x8 bh[4], bl[4];
        #pragma unroll
        for (int fn = 0; fn < 4; ++fn) {
            int off = kq * 2048 + (wn * 64 + fn * 16 + lrow) * 8;
            bh[fn] = *reinterpret_cast<const bf16x8*>(&sBhi[cur][off]);
            bl[fn] = *reinterpret_cast<const bf16x8*>(&sBlo[cur][off]);
        }
        // 4 phases x (2 fm x 4 fn x 3 terms = 24 MFMA)
        #pragma unroll
        for (int ph = 0; ph < 4; ++ph) {
            const int f0 = 2 * ph, f1 = 2 * ph + 1;
            int offA0 = kq * 2048 + (wm * 128 + f0 * 16 + lrow) * 8;
            int offA1 = kq * 2048 + (wm * 128 + f1 * 16 + lrow) * 8;
            bf16x8 ah0 = *reinterpret_cast<const bf16x8*>(&sAhi[cur][offA0]);
            bf16x8 al0 = *reinterpret_cast<const bf16x8*>(&sAlo[cur][offA0]);
            bf16x8 ah1 = *reinterpret_cast<const bf16x8*>(&sAhi[cur][offA1]);
            bf16x8 al1 = *reinterpret_cast<const bf16x8*>(&sAlo[cur][offA1]);
            asm volatile("s_waitcnt lgkmcnt(0)" ::: "memory");
            __builtin_amdgcn_sched_barrier(0);          // rule 18: pin MFMA after lgkm
            __builtin_amdgcn_s_setprio(1);
            #pragma unroll
            for (int fn = 0; fn < 4; ++fn) {
                acc[f0][fn] = MFMA(ah0, bh[fn], acc[f0][fn], 0, 0, 0);
                acc[f0][fn] = MFMA(ah0, bl[fn], acc[f0][fn], 0, 0, 0);
                acc[f0][fn] = MFMA(al0, bh[fn], acc[f0][fn], 0, 0, 0);
            }
            #pragma unroll
            for (int fn = 0; fn < 4; ++fn) {
                acc[f1][fn] = MFMA(ah1, bh[fn], acc[f1][fn], 0, 0, 0);
                acc[f1][fn] = MFMA(ah1, bl[fn], acc[f1][fn], 0, 0, 0);
                acc[f1][fn] = MFMA(al1, bh[fn], acc[f1][fn], 0, 0, 0);
            }
            __builtin_amdgcn_s_setprio(0);
            __builtin_amdgcn_sched_barrier(0);
            __builtin_amdgcn_s_barrier();   // phase boundary (last one guards dbuf reuse)
        }
    }
#undef STAGE

    // epilogue: C/D layout col=lane&15, row=(lane>>4)*4+i (m89-verified)
    #pragma unroll
    for (int fm = 0; fm < 8; ++fm) {
        long gmb = m0 + wm * 128 + fm * 16 + kq * 4;
        #pragma unroll
        for (int fn = 0; fn < 4; ++fn) {
            long gn = n0 + wn * 64 + fn * 16 + lrow;
            float bb = bias[gn];
            #pragma unroll
            for (int i = 0; i < 4; ++i)
                Cout[(gmb + i) * Nd + gn] = acc[fm][fn][i] + bb;
        }
    }
}

// ===========================================================================
// W' GEMM (split-K slabs): 128x128 tile, BK=32, 4 waves (2x2), dbuf 64KB
// (2 blocks/CU), counted vmcnt(8), setprio. A,B pre-split hi/lo, B as [N][K].
// slab z: koff = z*Kd, out offset z*Mtot*Nd, fp32 no-bias write.
// ===========================================================================
__global__ __launch_bounds__(256, 2)
void gemmW(const u16* __restrict__ Ahi, const u16* __restrict__ Alo,
           const u16* __restrict__ Bhi, const u16* __restrict__ Blo,
           float* __restrict__ Cout, int Kd, int Ld, int Nd)
{
    __shared__ __align__(16) u16 sAhi[2][4096];
    __shared__ __align__(16) u16 sAlo[2][4096];
    __shared__ __align__(16) u16 sBhi[2][4096];
    __shared__ __align__(16) u16 sBlo[2][4096];

    const int tid = threadIdx.x, lane = tid & 63, wave = tid >> 6;
    const int wm = wave >> 1, wn = wave & 1;
    const int lrow = lane & 15, kq = lane >> 4;

    const int nwg = gridDim.x * gridDim.y;
    const int lin = blockIdx.y * gridDim.x + blockIdx.x;
    const int lin2 = (lin & 7) * (nwg >> 3) + (lin >> 3);
    const int bx = lin2 % gridDim.x, by = lin2 / gridDim.x;
    const long m0 = (long)bx * 128;
    const long n0 = (long)by * 128;
    const long koff = (long)blockIdx.z * Kd;
    Cout += (size_t)blockIdx.z * (size_t)gridDim.x * 128 * Nd;

    const int i0 = wave * 2, i1 = i0 + 1;
    const int s0 = i0 & 3, h0 = i0 >> 2, s1 = i1 & 3, h1 = i1 >> 2;
    const int cb0 = s0 * 1024 + h0 * 512;
    const int cb1 = s1 * 1024 + h1 * 512;
    const long ga0 = (m0 + h0 * 64 + lane) * (long)Ld + koff + s0 * 8;
    const long ga1 = (m0 + h1 * 64 + lane) * (long)Ld + koff + s1 * 8;
    const long gb0 = (n0 + h0 * 64 + lane) * (long)Ld + koff + s0 * 8;
    const long gb1 = (n0 + h1 * 64 + lane) * (long)Ld + koff + s1 * 8;

    f32x4 acc[4][4];
    #pragma unroll
    for (int i = 0; i < 4; ++i)
        #pragma unroll
        for (int j = 0; j < 4; ++j)
            acc[i][j] = (f32x4){0.f, 0.f, 0.f, 0.f};

#define STAGEW(buf, kt) do { \
    LDSLOAD(Ahi + ga0 + (kt), &sAhi[buf][cb0]); \
    LDSLOAD(Ahi + ga1 + (kt), &sAhi[buf][cb1]); \
    LDSLOAD(Alo + ga0 + (kt), &sAlo[buf][cb0]); \
    LDSLOAD(Alo + ga1 + (kt), &sAlo[buf][cb1]); \
    LDSLOAD(Bhi + gb0 + (kt), &sBhi[buf][cb0]); \
    LDSLOAD(Bhi + gb1 + (kt), &sBhi[buf][cb1]); \
    LDSLOAD(Blo + gb0 + (kt), &sBlo[buf][cb0]); \
    LDSLOAD(Blo + gb1 + (kt), &sBlo[buf][cb1]); \
} while (0)

    const int NT = Kd >> 5;
    STAGEW(0, 0);

    for (int t = 0; t < NT; ++t) {
        const int cur = t & 1;
        if (t + 1 < NT) {
            STAGEW(cur ^ 1, (t + 1) << 5);
            asm volatile("s_waitcnt vmcnt(8)" ::: "memory");
        } else {
            asm volatile("s_waitcnt vmcnt(0)" ::: "memory");
        }
        __builtin_amdgcn_s_barrier();
        __builtin_amdgcn_sched_barrier(0);

        bf16x8 bh[4], bl[4];
        #pragma unroll
        for (int fn = 0; fn < 4; ++fn) {
            int off = kq * 1024 + (wn * 64 + fn * 16 + lrow) * 8;
            bh[fn] = *reinterpret_cast<const bf16x8*>(&sBhi[cur][off]);
            bl[fn] = *reinterpret_cast<const bf16x8*>(&sBlo[cur][off]);
        }
        #pragma unroll
        for (int fm = 0; fm < 4; ++fm) {
            int off = kq * 1024 + (wm * 64 + fm * 16 + lrow) * 8;
            bf16x8 ah = *reinterpret_cast<const bf16x8*>(&sAhi[cur][off]);
            bf16x8 al = *reinterpret_cast<const bf16x8*>(&sAlo[cur][off]);
            asm volatile("s_waitcnt lgkmcnt(0)" ::: "memory");
            __builtin_amdgcn_sched_barrier(0);
            __builtin_amdgcn_s_setprio(1);
            #pragma unroll
            for (int fn = 0; fn < 4; ++fn) {
                acc[fm][fn] = MFMA(ah, bh[fn], acc[fm][fn], 0, 0, 0);
                acc[fm][fn] = MFMA(ah, bl[fn], acc[fm][fn], 0, 0, 0);
                acc[fm][fn] = MFMA(al, bh[fn], acc[fm][fn], 0, 0, 0);
            }
            __builtin_amdgcn_s_setprio(0);
            __builtin_amdgcn_sched_barrier(0);
        }
        __builtin_amdgcn_s_barrier();
    }
#undef STAGEW

    #pragma unroll
    for (int fm = 0; fm < 4; ++fm) {
        long gmb = m0 + wm * 64 + fm * 16 + kq * 4;
        #pragma unroll
        for (int fn = 0; fn < 4; ++fn) {
            long gn = n0 + wn * 64 + fn * 16 + lrow;
            #pragma unroll
            for (int i = 0; i < 4; ++i)
                Cout[(gmb + i) * Nd + gn] = acc[fm][fn][i];
        }
    }
}

// ---------------------------------------------------------------------------
// 128x128 GEMM (round-3 structure) — fallback paths only.
// ---------------------------------------------------------------------------
template<int EPIL, int APRE, int BPRE>
__global__ __launch_bounds__(256)
void gemm3(const float* __restrict__ Af, const u16* __restrict__ Ahi, const u16* __restrict__ Alo,
           const float* __restrict__ Btf, const u16* __restrict__ Bhi, const u16* __restrict__ Blo,
           float* __restrict__ Cout, const float* __restrict__ bias,
           u16* __restrict__ Ohi, u16* __restrict__ Olo, int Kd, int Ld, int Nd)
{
    __shared__ __align__(16) u16 sAhi[4096];
    __shared__ __align__(16) u16 sAlo[4096];
    __shared__ __align__(16) u16 sBhi[4096];
    __shared__ __align__(16) u16 sBlo[4096];

    const int tid = threadIdx.x, lane = tid & 63, wave = tid >> 6;
    const int wm = wave >> 1, wn = wave & 1;
    const int lrow = lane & 15, kq = lane >> 4;

    const int nwg = gridDim.x * gridDim.y;
    const int lin = blockIdx.y * gridDim.x + blockIdx.x;
    const int lin2 = (lin & 7) * (nwg >> 3) + (lin >> 3);
    const int bx = lin2 % gridDim.x, by = lin2 / gridDim.x;
    const long m0 = (long)bx * 128;
    const long n0 = (long)by * 128;
    const long koff = (long)blockIdx.z * Kd;
    if (EPIL == 2) Cout += (size_t)blockIdx.z * (size_t)gridDim.x * 128 * Nd;

    const int idx0 = wave * 2, idx1 = wave * 2 + 1;
    const int s0 = idx0 & 3, h0 = idx0 >> 2;
    const int s1 = idx1 & 3, h1 = idx1 >> 2;
    const int cb0 = s0 * 1024 + h0 * 512;
    const int cb1 = s1 * 1024 + h1 * 512;
    const long ga0 = (m0 + h0 * 64 + lane) * (long)Ld + koff + s0 * 8;
    const long ga1 = (m0 + h1 * 64 + lane) * (long)Ld + koff + s1 * 8;
    const long gb0 = (n0 + h0 * 64 + lane) * (long)Ld + koff + s0 * 8;
    const long gb1 = (n0 + h1 * 64 + lane) * (long)Ld + koff + s1 * 8;

    f32x4 acc[4][4];
    #pragma unroll
    for (int i = 0; i < 4; ++i)
        #pragma unroll
        for (int j = 0; j < 4; ++j)
            acc[i][j] = (f32x4){0.f, 0.f, 0.f, 0.f};

    float4 av[4], bvv[4];
    if (!APRE) {
        #pragma unroll
        for (int i = 0; i < 4; ++i) {
            int ch = tid + i * 256, r = ch >> 3, c4 = ch & 7;
            av[i] = *reinterpret_cast<const float4*>(Af + (m0 + r) * (long)Ld + koff + c4 * 4);
        }
    }
    if (!BPRE) {
        #pragma unroll
        for (int i = 0; i < 4; ++i) {
            int ch = tid + i * 256, r = ch >> 3, c4 = ch & 7;
            bvv[i] = *reinterpret_cast<const float4*>(Btf + (n0 + r) * (long)Ld + koff + c4 * 4);
        }
    }

    for (int kt = 0; kt < Kd; kt += 32) {
        if (APRE) {
            LDSLOAD(Ahi + ga0 + kt, sAhi + cb0);
            LDSLOAD(Ahi + ga1 + kt, sAhi + cb1);
            LDSLOAD(Alo + ga0 + kt, sAlo + cb0);
            LDSLOAD(Alo + ga1 + kt, sAlo + cb1);
        } else {
            #pragma unroll
            for (int i = 0; i < 4; ++i) {
                int ch = tid + i * 256, r = ch >> 3, c4 = ch & 7;
                int off = (c4 >> 1) * 1024 + r * 8 + (c4 & 1) * 4;
                ushort4 h, l;
                h.x = f2bf(av[i].x); l.x = f2bf(av[i].x - bf2f(h.x));
                h.y = f2bf(av[i].y); l.y = f2bf(av[i].y - bf2f(h.y));
                h.z = f2bf(av[i].z); l.z = f2bf(av[i].z - bf2f(h.z));
                h.w = f2bf(av[i].w); l.w = f2bf(av[i].w - bf2f(h.w));
                *reinterpret_cast<ushort4*>(&sAhi[off]) = h;
                *reinterpret_cast<ushort4*>(&sAlo[off]) = l;
            }
        }
        if (BPRE) {
            LDSLOAD(Bhi + gb0 + kt, sBhi + cb0);
            LDSLOAD(Bhi + gb1 + kt, sBhi + cb1);
            LDSLOAD(Blo + gb0 + kt, sBlo + cb0);
            LDSLOAD(Blo + gb1 + kt, sBlo + cb1);
        } else {
            #pragma unroll
            for (int i = 0; i < 4; ++i) {
                int ch = tid + i * 256, r = ch >> 3, c4 = ch & 7;
                int off = (c4 >> 1) * 1024 + r * 8 + (c4 & 1) * 4;
                ushort4 h, l;
                h.x = f2bf(bvv[i].x); l.x = f2bf(bvv[i].x - bf2f(h.x));
                h.y = f2bf(bvv[i].y); l.y = f2bf(bvv[i].y - bf2f(h.y));
                h.z = f2bf(bvv[i].z); l.z = f2bf(bvv[i].z - bf2f(h.z));
                h.w = f2bf(bvv[i].w); l.w = f2bf(bvv[i].w - bf2f(h.w));
                *reinterpret_cast<ushort4*>(&sBhi[off]) = h;
                *reinterpret_cast<ushort4*>(&sBlo[off]) = l;
            }
        }

        __syncthreads();

        if (!APRE && kt + 32 < Kd) {
            #pragma unroll
            for (int i = 0; i < 4; ++i) {
                int ch = tid + i * 256, r = ch >> 3, c4 = ch & 7;
                av[i] = *reinterpret_cast<const float4*>(Af + (m0 + r) * (long)Ld + koff + kt + 32 + c4 * 4);
            }
        }
        if (!BPRE && kt + 32 < Kd) {
            #pragma unroll
            for (int i = 0; i < 4; ++i) {
                int ch = tid + i * 256, r = ch >> 3, c4 = ch & 7;
                bvv[i] = *reinterpret_cast<const float4*>(Btf + (n0 + r) * (long)Ld + koff + kt + 32 + c4 * 4);
            }
        }

        bf16x8 bh[4], bl[4];
        #pragma unroll
        for (int fn = 0; fn < 4; ++fn) {
            int r = wn * 64 + fn * 16 + lrow;
            bh[fn] = *reinterpret_cast<const bf16x8*>(&sBhi[kq * 1024 + r * 8]);
            bl[fn] = *reinterpret_cast<const bf16x8*>(&sBlo[kq * 1024 + r * 8]);
        }
        #pragma unroll
        for (int fm = 0; fm < 4; ++fm) {
            int r = wm * 64 + fm * 16 + lrow;
            bf16x8 ah = *reinterpret_cast<const bf16x8*>(&sAhi[kq * 1024 + r * 8]);
            bf16x8 al = *reinterpret_cast<const bf16x8*>(&sAlo[kq * 1024 + r * 8]);
            #pragma unroll
            for (int fn = 0; fn < 4; ++fn) {
                acc[fm][fn] = MFMA(ah, bh[fn], acc[fm][fn], 0, 0, 0);
                acc[fm][fn] = MFMA(ah, bl[fn], acc[fm][fn], 0, 0, 0);
                acc[fm][fn] = MFMA(al, bh[fn], acc[fm][fn], 0, 0, 0);
            }
        }

        __syncthreads();
    }

    #pragma unroll
    for (int fm = 0; fm < 4; ++fm) {
        long gmb = m0 + wm * 64 + fm * 16 + kq * 4;
        #pragma unroll
        for (int fn = 0; fn < 4; ++fn) {
            long gn = n0 + wn * 64 + fn * 16 + lrow;
            float bb = (EPIL == 0) ? bias[gn] : 0.0f;
            #pragma unroll
            for (int i = 0; i < 4; ++i) {
                float w = acc[fm][fn][i];
                if (EPIL == 0) {
                    Cout[(gmb + i) * Nd + gn] = w + bb;
                } else if (EPIL == 2) {
                    Cout[(gmb + i) * Nd + gn] = w;
                } else {
                    u16 h = f2bf(w);
                    Ohi[(gmb + i) * Nd + gn] = h;
                    Olo[(gmb + i) * Nd + gn] = f2bf(w - bf2f(h));
                }
            }
        }
    }
}

// ---------------------------------------------------------------------------
// out = x @ (Wv @ Wc) + (bv @ Wc + bc)
//   (attention collapses: einsum sums att over j; softmax rows sum to 1 -> y == v)
// ---------------------------------------------------------------------------
extern "C" void kernel_launch(void* const* d_in, const int* in_sizes, int n_in,
                              void* d_out, int out_size, void* d_ws, size_t ws_size,
                              hipStream_t stream) {
    const float* x  = (const float*)d_in[0];
    const float* Wv = (const float*)d_in[5];
    const float* bv = (const float*)d_in[6];
    const float* Wc = (const float*)d_in[7];
    const float* bc = (const float*)d_in[8];
    float* out = (float*)d_out;

    char* ws = (char*)d_ws;
    const size_t MB = 1024 * 1024;

    float* bp = (float*)ws;                 // 8KB reserved
    hipMemsetAsync(bp, 0, ED * sizeof(float), stream);
    bias_kernel<<<dim3(ED / 256, ED / 64), 256, 0, stream>>>(bv, Wc, bc, bp);

    if (ws_size >= 80 * MB + 8192) {
        // FULL path
        u16* Wpt_hi = (u16*)(ws + 8192);
        u16* Wpt_lo = (u16*)(ws + 8192 + 8 * MB);
        char* R = ws + 8192 + 16 * MB;          // 64MB region, two lifetimes
        u16* Wct_hi = (u16*)R;                  // phase 1
        u16* Wct_lo = (u16*)(R + 8 * MB);
        u16* Wv_hi  = (u16*)(R + 16 * MB);
        u16* Wv_lo  = (u16*)(R + 24 * MB);
        float* slab = (float*)(R + 32 * MB);    // 2 x 16MB
        u16* x_hi   = (u16*)R;                  // phase 2 (overwrites phase 1)
        u16* x_lo   = (u16*)(R + 32 * MB);

        transpose_split<<<dim3(64, 64), 256, 0, stream>>>(Wc, Wct_hi, Wct_lo, ED);
        split_kernel<<<2048, 256, 0, stream>>>(Wv, Wv_hi, Wv_lo, ED * ED / 4);
        // W'^T = Wc^T @ Wv^T, split-K=2 into fp32 slabs (dbuf counted-vmcnt kernel)
        gemmW<<<dim3(16, 16, 2), 256, 0, stream>>>(
            Wct_hi, Wct_lo, Wv_hi, Wv_lo, slab, ED / 2, ED, ED);
        reduce2_split<<<2048, 256, 0, stream>>>(slab, slab + (size_t)ED * ED,
                                                Wpt_hi, Wpt_lo, ED * ED / 4);
        split_kernel<<<2048, 256, 0, stream>>>(x, x_hi, x_lo, MR * ED / 4);
        // out = x @ W' + bp  (256^2 4-phase pipeline)
        gemm256<<<dim3(MR / 256, ED / 256), 512, 0, stream>>>(
            x_hi, x_lo, Wpt_hi, Wpt_lo, out, bp, ED, ED);
    } else if (ws_size >= 48 * MB + 8192) {
        // MID path
        u16* Wpt_hi = (u16*)(ws + 8192);
        u16* Wpt_lo = (u16*)(ws + 8192 + 8 * MB);
        char* R = ws + 8192 + 16 * MB;
        u16* Wct_hi = (u16*)R;
        u16* Wct_lo = (u16*)(R + 8 * MB);
        u16* Wv_hi  = (u16*)(R + 16 * MB);
        u16* Wv_lo  = (u16*)(R + 24 * MB);

        transpose_split<<<dim3(64, 64), 256, 0, stream>>>(Wc, Wct_hi, Wct_lo, ED);
        split_kernel<<<2048, 256, 0, stream>>>(Wv, Wv_hi, Wv_lo, ED * ED / 4);
        gemm3<1, 1, 1><<<dim3(16, 16), 256, 0, stream>>>(
            nullptr, Wct_hi, Wct_lo, nullptr, Wv_hi, Wv_lo,
            nullptr, nullptr, Wpt_hi, Wpt_lo, ED, ED, ED);
        gemm3<0, 0, 1><<<dim3(64, 16), 256, 0, stream>>>(
            x, nullptr, nullptr, nullptr, Wpt_hi, Wpt_lo,
            out, bp, nullptr, nullptr, ED, ED, ED);
    } else {
        // MINIMAL path (~32MB)
        float* Wct  = (float*)(ws + 8192);
        u16* Wpt_hi = (u16*)(ws + 8192 + 16 * MB);
        u16* Wpt_lo = (u16*)(ws + 8192 + 24 * MB);

        transpose_f32<<<dim3(64, 64), 256, 0, stream>>>(Wc, Wct, ED);
        gemm3<1, 0, 0><<<dim3(16, 16), 256, 0, stream>>>(
            Wct, nullptr, nullptr, Wv, nullptr, nullptr,
            nullptr, nullptr, Wpt_hi, Wpt_lo, ED, ED, ED);
        gemm3<0, 0, 1><<<dim3(64, 16), 256, 0, stream>>>(
            x, nullptr, nullptr, nullptr, Wpt_hi, Wpt_lo,
            out, bp, nullptr, nullptr, ED, ED, ED);
    }
}

// Round 6
// 378.121 us; speedup vs baseline: 1.4755x; 1.4755x over previous
//
#include <hip/hip_runtime.h>

#define ED 2048
#define MR 8192

typedef unsigned short u16;
typedef _Float16 f16;
typedef __attribute__((ext_vector_type(8))) __bf16 bf16x8;
typedef __attribute__((ext_vector_type(8))) _Float16 f16x8;
typedef __attribute__((ext_vector_type(4))) float f32x4;

__device__ __forceinline__ u16 f2bf(float f){ __bf16 h=(__bf16)f; return __builtin_bit_cast(u16,h); }
__device__ __forceinline__ float bf2f(u16 u){ __bf16 h=__builtin_bit_cast(__bf16,u); return (float)h; }

#define MFMA16 __builtin_amdgcn_mfma_f32_16x16x32_f16
#define MFMAB  __builtin_amdgcn_mfma_f32_16x16x32_bf16

// async global->LDS, 16B per lane; LDS dest is wave-uniform base + lane*16
#define LDSLOAD(gp, lp) __builtin_amdgcn_global_load_lds( \
    (const __attribute__((address_space(1))) unsigned int*)(gp), \
    (__attribute__((address_space(3))) unsigned int*)(lp), 16, 0, 0)

// ---------------------------------------------------------------------------
// cast fp32 -> fp16 (8 elems/thread, 16B stores, grid-stride)
// ---------------------------------------------------------------------------
__global__ void cast16(const float* __restrict__ in, f16* __restrict__ out, int n8) {
    int i = blockIdx.x * 256 + threadIdx.x;
    const int stride = gridDim.x * 256;
    for (; i < n8; i += stride) {
        float4 a = reinterpret_cast<const float4*>(in)[2 * i];
        float4 b = reinterpret_cast<const float4*>(in)[2 * i + 1];
        f16x8 v;
        v[0] = (f16)a.x; v[1] = (f16)a.y; v[2] = (f16)a.z; v[3] = (f16)a.w;
        v[4] = (f16)b.x; v[5] = (f16)b.y; v[6] = (f16)b.z; v[7] = (f16)b.w;
        *reinterpret_cast<f16x8*>(out + (size_t)i * 8) = v;
    }
}

// ---------------------------------------------------------------------------
// 32x32 tiled transpose fp32 -> fp16
// ---------------------------------------------------------------------------
__global__ void transpose_f16(const float* __restrict__ in, f16* __restrict__ out, int n) {
    __shared__ float tile[32][33];
    const int bx = blockIdx.x * 32, by = blockIdx.y * 32;
    const int tx = threadIdx.x & 31, ty = threadIdx.x >> 5;
    #pragma unroll
    for (int r = ty; r < 32; r += 8)
        tile[r][tx] = in[(size_t)(by + r) * n + bx + tx];
    __syncthreads();
    #pragma unroll
    for (int r = ty; r < 32; r += 8)
        out[(size_t)(bx + r) * n + by + tx] = (f16)tile[tx][r];
}

// ---------------------------------------------------------------------------
// 32x32 tiled transpose fp32 -> fp32 (fallback path)
// ---------------------------------------------------------------------------
__global__ void transpose_f32(const float* __restrict__ in, float* __restrict__ out, int n) {
    __shared__ float tile[32][33];
    const int bx = blockIdx.x * 32, by = blockIdx.y * 32;
    const int tx = threadIdx.x & 31, ty = threadIdx.x >> 5;
    #pragma unroll
    for (int r = ty; r < 32; r += 8)
        tile[r][tx] = in[(size_t)(by + r) * n + bx + tx];
    __syncthreads();
    #pragma unroll
    for (int r = ty; r < 32; r += 8)
        out[(size_t)(bx + r) * n + by + tx] = tile[tx][r];
}

// ---------------------------------------------------------------------------
// split fp32 -> hi/lo bf16 (fallback path)
// ---------------------------------------------------------------------------
__global__ void split_kernel(const float* __restrict__ in, u16* __restrict__ hi,
                             u16* __restrict__ lo, int n4) {
    int i = blockIdx.x * 256 + threadIdx.x;
    const int stride = gridDim.x * 256;
    for (; i < n4; i += stride) {
        float4 v = reinterpret_cast<const float4*>(in)[i];
        ushort4 h, l;
        h.x = f2bf(v.x); l.x = f2bf(v.x - bf2f(h.x));
        h.y = f2bf(v.y); l.y = f2bf(v.y - bf2f(h.y));
        h.z = f2bf(v.z); l.z = f2bf(v.z - bf2f(h.z));
        h.w = f2bf(v.w); l.w = f2bf(v.w - bf2f(h.w));
        reinterpret_cast<ushort4*>(hi)[i] = h;
        reinterpret_cast<ushort4*>(lo)[i] = l;
    }
}

// ---------------------------------------------------------------------------
// bp[n] += (bc[n] if first chunk) + sum_{j chunk of 64} bv[j]*Wc[j][n]
// ---------------------------------------------------------------------------
__global__ void bias_kernel(const float* __restrict__ bv, const float* __restrict__ Wc,
                            const float* __restrict__ bc, float* __restrict__ bp) {
    const int n = blockIdx.x * 256 + threadIdx.x;
    const int j0 = blockIdx.y * 64;
    float s = (blockIdx.y == 0) ? bc[n] : 0.0f;
    #pragma unroll 4
    for (int j = 0; j < 64; ++j)
        s += bv[j0 + j] * Wc[(size_t)(j0 + j) * ED + n];
    atomicAdd(&bp[n], s);
}

// ===========================================================================
// MAIN GEMM (fp16 single-pass): 256x256, BK=32, 8 waves (2x4), dbuf 64KB LDS,
// round-4-proven 2-phase discipline: STAGE(t+1) -> vmcnt(4) -> barrier ->
// compiler-scheduled {12 ds_read_b128 + 32 MFMA} -> barrier.
// LDS slot-major per plane (256x32 f16): elem (r,k) at (k>>3)*2048 + r*8 + (k&7).
// Staging call c in [0,16): k-slot c>>2, rows (c&3)*64+lane, LDS base c*512.
// ===========================================================================
__global__ __launch_bounds__(512, 1)
void gemm256f(const f16* __restrict__ A, const f16* __restrict__ B,
              float* __restrict__ Cout, const float* __restrict__ bias,
              int Kd, int Nd)
{
    __shared__ __align__(16) f16 sA[2][8192];
    __shared__ __align__(16) f16 sB[2][8192];

    const int tid = threadIdx.x, lane = tid & 63, wave = tid >> 6;
    const int wm = wave >> 2, wn = wave & 3;          // 2 x 4 wave grid
    const int lrow = lane & 15, kq = lane >> 4;

    // XCD-chunked bijective swizzle (nwg = 256, %8 == 0)
    const int nwg = gridDim.x * gridDim.y;
    const int lin = blockIdx.y * gridDim.x + blockIdx.x;
    const int lin2 = (lin & 7) * (nwg >> 3) + (lin >> 3);
    const int bx = lin2 % gridDim.x, by = lin2 / gridDim.x;
    const long m0 = (long)bx * 256;
    const long n0 = (long)by * 256;

    const int c0 = wave * 2, c1 = c0 + 1;
    const int lb0 = c0 * 512, lb1 = c1 * 512;
    const long ga0 = (m0 + (c0 & 3) * 64 + lane) * (long)Kd + (c0 >> 2) * 8;
    const long ga1 = (m0 + (c1 & 3) * 64 + lane) * (long)Kd + (c1 >> 2) * 8;
    const long gb0 = (n0 + (c0 & 3) * 64 + lane) * (long)Kd + (c0 >> 2) * 8;
    const long gb1 = (n0 + (c1 & 3) * 64 + lane) * (long)Kd + (c1 >> 2) * 8;

    f32x4 acc[8][4];
    #pragma unroll
    for (int i = 0; i < 8; ++i)
        #pragma unroll
        for (int j = 0; j < 4; ++j)
            acc[i][j] = (f32x4){0.f, 0.f, 0.f, 0.f};

#define STAGE(buf, kt) do { \
    LDSLOAD(A + ga0 + (kt), &sA[buf][lb0]); \
    LDSLOAD(A + ga1 + (kt), &sA[buf][lb1]); \
    LDSLOAD(B + gb0 + (kt), &sB[buf][lb0]); \
    LDSLOAD(B + gb1 + (kt), &sB[buf][lb1]); \
} while (0)

    const int NT = Kd >> 5;   // 64
    STAGE(0, 0);

    for (int t = 0; t < NT; ++t) {
        const int cur = t & 1;
        if (t + 1 < NT) {
            STAGE(cur ^ 1, (t + 1) << 5);
            asm volatile("s_waitcnt vmcnt(4)" ::: "memory");   // stage(t) done, stage(t+1) flying
        } else {
            asm volatile("s_waitcnt vmcnt(0)" ::: "memory");
        }
        __builtin_amdgcn_s_barrier();       // buf[cur] ready on all waves
        __builtin_amdgcn_sched_barrier(0);

        f16x8 bf[4];
        #pragma unroll
        for (int fn = 0; fn < 4; ++fn) {
            int off = kq * 2048 + (wn * 64 + fn * 16 + lrow) * 8;
            bf[fn] = *reinterpret_cast<const f16x8*>(&sB[cur][off]);
        }
        #pragma unroll
        for (int fm = 0; fm < 8; ++fm) {
            int off = kq * 2048 + (wm * 128 + fm * 16 + lrow) * 8;
            f16x8 af = *reinterpret_cast<const f16x8*>(&sA[cur][off]);
            #pragma unroll
            for (int fn = 0; fn < 4; ++fn)
                acc[fm][fn] = MFMA16(af, bf[fn], acc[fm][fn], 0, 0, 0);
        }

        __builtin_amdgcn_sched_barrier(0);
        __builtin_amdgcn_s_barrier();       // all waves done reading buf[cur]
    }
#undef STAGE

    // epilogue: C/D layout col=lane&15, row=(lane>>4)*4+i (m89-verified, dtype-indep)
    #pragma unroll
    for (int fm = 0; fm < 8; ++fm) {
        long gmb = m0 + wm * 128 + fm * 16 + kq * 4;
        #pragma unroll
        for (int fn = 0; fn < 4; ++fn) {
            long gn = n0 + wn * 64 + fn * 16 + lrow;
            float bb = bias[gn];
            #pragma unroll
            for (int i = 0; i < 4; ++i)
                Cout[(gmb + i) * Nd + gn] = acc[fm][fn][i] + bb;
        }
    }
}

// ===========================================================================
// W' GEMM (fp16): 128x128 tile, 4 waves (2x2), dbuf 32KB, counted vmcnt(4).
// C[m][n] = A[m][K] * B[K][n], B given transposed [n][K]; writes fp16 C.
// Staging call c in [0,8) per plane: slot c>>1, half c&1, LDS base c*512;
// global row (c&1)*64+lane, cols (c>>1)*8... wave w handles c=w*2, w*2+1.
// ===========================================================================
__global__ __launch_bounds__(256, 2)
void gemmW16(const f16* __restrict__ A, const f16* __restrict__ B,
             f16* __restrict__ Cout, int Kd, int Nd)
{
    __shared__ __align__(16) f16 sA[2][4096];
    __shared__ __align__(16) f16 sB[2][4096];

    const int tid = threadIdx.x, lane = tid & 63, wave = tid >> 6;
    const int wm = wave >> 1, wn = wave & 1;
    const int lrow = lane & 15, kq = lane >> 4;

    const int nwg = gridDim.x * gridDim.y;
    const int lin = blockIdx.y * gridDim.x + blockIdx.x;
    const int lin2 = (lin & 7) * (nwg >> 3) + (lin >> 3);
    const int bx = lin2 % gridDim.x, by = lin2 / gridDim.x;
    const long m0 = (long)bx * 128;
    const long n0 = (long)by * 128;

    const int c0 = wave * 2, c1 = c0 + 1;
    const int lb0 = c0 * 512, lb1 = c1 * 512;
    const long ga0 = (m0 + (c0 & 1) * 64 + lane) * (long)Kd + (c0 >> 1) * 8;
    const long ga1 = (m0 + (c1 & 1) * 64 + lane) * (long)Kd + (c1 >> 1) * 8;
    const long gb0 = (n0 + (c0 & 1) * 64 + lane) * (long)Kd + (c0 >> 1) * 8;
    const long gb1 = (n0 + (c1 & 1) * 64 + lane) * (long)Kd + (c1 >> 1) * 8;

    f32x4 acc[4][4];
    #pragma unroll
    for (int i = 0; i < 4; ++i)
        #pragma unroll
        for (int j = 0; j < 4; ++j)
            acc[i][j] = (f32x4){0.f, 0.f, 0.f, 0.f};

#define STAGEW(buf, kt) do { \
    LDSLOAD(A + ga0 + (kt), &sA[buf][lb0]); \
    LDSLOAD(A + ga1 + (kt), &sA[buf][lb1]); \
    LDSLOAD(B + gb0 + (kt), &sB[buf][lb0]); \
    LDSLOAD(B + gb1 + (kt), &sB[buf][lb1]); \
} while (0)

    const int NT = Kd >> 5;
    STAGEW(0, 0);

    for (int t = 0; t < NT; ++t) {
        const int cur = t & 1;
        if (t + 1 < NT) {
            STAGEW(cur ^ 1, (t + 1) << 5);
            asm volatile("s_waitcnt vmcnt(4)" ::: "memory");
        } else {
            asm volatile("s_waitcnt vmcnt(0)" ::: "memory");
        }
        __builtin_amdgcn_s_barrier();
        __builtin_amdgcn_sched_barrier(0);

        f16x8 bf[4];
        #pragma unroll
        for (int fn = 0; fn < 4; ++fn) {
            int off = kq * 1024 + (wn * 64 + fn * 16 + lrow) * 8;
            bf[fn] = *reinterpret_cast<const f16x8*>(&sB[cur][off]);
        }
        #pragma unroll
        for (int fm = 0; fm < 4; ++fm) {
            int off = kq * 1024 + (wm * 64 + fm * 16 + lrow) * 8;
            f16x8 af = *reinterpret_cast<const f16x8*>(&sA[cur][off]);
            #pragma unroll
            for (int fn = 0; fn < 4; ++fn)
                acc[fm][fn] = MFMA16(af, bf[fn], acc[fm][fn], 0, 0, 0);
        }

        __builtin_amdgcn_sched_barrier(0);
        __builtin_amdgcn_s_barrier();
    }
#undef STAGEW

    #pragma unroll
    for (int fm = 0; fm < 4; ++fm) {
        long gmb = m0 + wm * 64 + fm * 16 + kq * 4;
        #pragma unroll
        for (int fn = 0; fn < 4; ++fn) {
            long gn = n0 + wn * 64 + fn * 16 + lrow;
            #pragma unroll
            for (int i = 0; i < 4; ++i)
                Cout[(gmb + i) * Nd + gn] = (f16)acc[fm][fn][i];
        }
    }
}

// ---------------------------------------------------------------------------
// 128x128 3-term bf16-split GEMM — MINIMAL fallback path only (round-3 code).
// ---------------------------------------------------------------------------
template<int EPIL, int APRE, int BPRE>
__global__ __launch_bounds__(256)
void gemm3(const float* __restrict__ Af, const u16* __restrict__ Ahi, const u16* __restrict__ Alo,
           const float* __restrict__ Btf, const u16* __restrict__ Bhi, const u16* __restrict__ Blo,
           float* __restrict__ Cout, const float* __restrict__ bias,
           u16* __restrict__ Ohi, u16* __restrict__ Olo, int Kd, int Ld, int Nd)
{
    __shared__ __align__(16) u16 sAhi[4096];
    __shared__ __align__(16) u16 sAlo[4096];
    __shared__ __align__(16) u16 sBhi[4096];
    __shared__ __align__(16) u16 sBlo[4096];

    const int tid = threadIdx.x, lane = tid & 63, wave = tid >> 6;
    const int wm = wave >> 1, wn = wave & 1;
    const int lrow = lane & 15, kq = lane >> 4;

    const int nwg = gridDim.x * gridDim.y;
    const int lin = blockIdx.y * gridDim.x + blockIdx.x;
    const int lin2 = (lin & 7) * (nwg >> 3) + (lin >> 3);
    const int bx = lin2 % gridDim.x, by = lin2 / gridDim.x;
    const long m0 = (long)bx * 128;
    const long n0 = (long)by * 128;
    const long koff = (long)blockIdx.z * Kd;
    if (EPIL == 2) Cout += (size_t)blockIdx.z * (size_t)gridDim.x * 128 * Nd;

    const int idx0 = wave * 2, idx1 = wave * 2 + 1;
    const int s0 = idx0 & 3, h0 = idx0 >> 2;
    const int s1 = idx1 & 3, h1 = idx1 >> 2;
    const int cb0 = s0 * 1024 + h0 * 512;
    const int cb1 = s1 * 1024 + h1 * 512;
    const long ga0 = (m0 + h0 * 64 + lane) * (long)Ld + koff + s0 * 8;
    const long ga1 = (m0 + h1 * 64 + lane) * (long)Ld + koff + s1 * 8;
    const long gb0 = (n0 + h0 * 64 + lane) * (long)Ld + koff + s0 * 8;
    const long gb1 = (n0 + h1 * 64 + lane) * (long)Ld + koff + s1 * 8;

    f32x4 acc[4][4];
    #pragma unroll
    for (int i = 0; i < 4; ++i)
        #pragma unroll
        for (int j = 0; j < 4; ++j)
            acc[i][j] = (f32x4){0.f, 0.f, 0.f, 0.f};

    float4 av[4], bvv[4];
    if (!APRE) {
        #pragma unroll
        for (int i = 0; i < 4; ++i) {
            int ch = tid + i * 256, r = ch >> 3, c4 = ch & 7;
            av[i] = *reinterpret_cast<const float4*>(Af + (m0 + r) * (long)Ld + koff + c4 * 4);
        }
    }
    if (!BPRE) {
        #pragma unroll
        for (int i = 0; i < 4; ++i) {
            int ch = tid + i * 256, r = ch >> 3, c4 = ch & 7;
            bvv[i] = *reinterpret_cast<const float4*>(Btf + (n0 + r) * (long)Ld + koff + c4 * 4);
        }
    }

    for (int kt = 0; kt < Kd; kt += 32) {
        if (APRE) {
            LDSLOAD(Ahi + ga0 + kt, sAhi + cb0);
            LDSLOAD(Ahi + ga1 + kt, sAhi + cb1);
            LDSLOAD(Alo + ga0 + kt, sAlo + cb0);
            LDSLOAD(Alo + ga1 + kt, sAlo + cb1);
        } else {
            #pragma unroll
            for (int i = 0; i < 4; ++i) {
                int ch = tid + i * 256, r = ch >> 3, c4 = ch & 7;
                int off = (c4 >> 1) * 1024 + r * 8 + (c4 & 1) * 4;
                ushort4 h, l;
                h.x = f2bf(av[i].x); l.x = f2bf(av[i].x - bf2f(h.x));
                h.y = f2bf(av[i].y); l.y = f2bf(av[i].y - bf2f(h.y));
                h.z = f2bf(av[i].z); l.z = f2bf(av[i].z - bf2f(h.z));
                h.w = f2bf(av[i].w); l.w = f2bf(av[i].w - bf2f(h.w));
                *reinterpret_cast<ushort4*>(&sAhi[off]) = h;
                *reinterpret_cast<ushort4*>(&sAlo[off]) = l;
            }
        }
        if (BPRE) {
            LDSLOAD(Bhi + gb0 + kt, sBhi + cb0);
            LDSLOAD(Bhi + gb1 + kt, sBhi + cb1);
            LDSLOAD(Blo + gb0 + kt, sBlo + cb0);
            LDSLOAD(Blo + gb1 + kt, sBlo + cb1);
        } else {
            #pragma unroll
            for (int i = 0; i < 4; ++i) {
                int ch = tid + i * 256, r = ch >> 3, c4 = ch & 7;
                int off = (c4 >> 1) * 1024 + r * 8 + (c4 & 1) * 4;
                ushort4 h, l;
                h.x = f2bf(bvv[i].x); l.x = f2bf(bvv[i].x - bf2f(h.x));
                h.y = f2bf(bvv[i].y); l.y = f2bf(bvv[i].y - bf2f(h.y));
                h.z = f2bf(bvv[i].z); l.z = f2bf(bvv[i].z - bf2f(h.z));
                h.w = f2bf(bvv[i].w); l.w = f2bf(bvv[i].w - bf2f(h.w));
                *reinterpret_cast<ushort4*>(&sBhi[off]) = h;
                *reinterpret_cast<ushort4*>(&sBlo[off]) = l;
            }
        }

        __syncthreads();

        if (!APRE && kt + 32 < Kd) {
            #pragma unroll
            for (int i = 0; i < 4; ++i) {
                int ch = tid + i * 256, r = ch >> 3, c4 = ch & 7;
                av[i] = *reinterpret_cast<const float4*>(Af + (m0 + r) * (long)Ld + koff + kt + 32 + c4 * 4);
            }
        }
        if (!BPRE && kt + 32 < Kd) {
            #pragma unroll
            for (int i = 0; i < 4; ++i) {
                int ch = tid + i * 256, r = ch >> 3, c4 = ch & 7;
                bvv[i] = *reinterpret_cast<const float4*>(Btf + (n0 + r) * (long)Ld + koff + kt + 32 + c4 * 4);
            }
        }

        bf16x8 bh[4], bl[4];
        #pragma unroll
        for (int fn = 0; fn < 4; ++fn) {
            int r = wn * 64 + fn * 16 + lrow;
            bh[fn] = *reinterpret_cast<const bf16x8*>(&sBhi[kq * 1024 + r * 8]);
            bl[fn] = *reinterpret_cast<const bf16x8*>(&sBlo[kq * 1024 + r * 8]);
        }
        #pragma unroll
        for (int fm = 0; fm < 4; ++fm) {
            int r = wm * 64 + fm * 16 + lrow;
            bf16x8 ah = *reinterpret_cast<const bf16x8*>(&sAhi[kq * 1024 + r * 8]);
            bf16x8 al = *reinterpret_cast<const bf16x8*>(&sAlo[kq * 1024 + r * 8]);
            #pragma unroll
            for (int fn = 0; fn < 4; ++fn) {
                acc[fm][fn] = MFMAB(ah, bh[fn], acc[fm][fn], 0, 0, 0);
                acc[fm][fn] = MFMAB(ah, bl[fn], acc[fm][fn], 0, 0, 0);
                acc[fm][fn] = MFMAB(al, bh[fn], acc[fm][fn], 0, 0, 0);
            }
        }

        __syncthreads();
    }

    #pragma unroll
    for (int fm = 0; fm < 4; ++fm) {
        long gmb = m0 + wm * 64 + fm * 16 + kq * 4;
        #pragma unroll
        for (int fn = 0; fn < 4; ++fn) {
            long gn = n0 + wn * 64 + fn * 16 + lrow;
            float bb = (EPIL == 0) ? bias[gn] : 0.0f;
            #pragma unroll
            for (int i = 0; i < 4; ++i) {
                float w = acc[fm][fn][i];
                if (EPIL == 0) {
                    Cout[(gmb + i) * Nd + gn] = w + bb;
                } else if (EPIL == 2) {
                    Cout[(gmb + i) * Nd + gn] = w;
                } else {
                    u16 h = f2bf(w);
                    Ohi[(gmb + i) * Nd + gn] = h;
                    Olo[(gmb + i) * Nd + gn] = f2bf(w - bf2f(h));
                }
            }
        }
    }
}

// ---------------------------------------------------------------------------
// out = x @ (Wv @ Wc) + (bv @ Wc + bc)
//   (attention collapses: einsum sums att over j; softmax rows sum to 1 -> y == v)
// ---------------------------------------------------------------------------
extern "C" void kernel_launch(void* const* d_in, const int* in_sizes, int n_in,
                              void* d_out, int out_size, void* d_ws, size_t ws_size,
                              hipStream_t stream) {
    const float* x  = (const float*)d_in[0];
    const float* Wv = (const float*)d_in[5];
    const float* bv = (const float*)d_in[6];
    const float* Wc = (const float*)d_in[7];
    const float* bc = (const float*)d_in[8];
    float* out = (float*)d_out;

    char* ws = (char*)d_ws;
    const size_t MB = 1024 * 1024;

    float* bp = (float*)ws;                 // 8KB reserved
    hipMemsetAsync(bp, 0, ED * sizeof(float), stream);
    bias_kernel<<<dim3(ED / 256, ED / 64), 256, 0, stream>>>(bv, Wc, bc, bp);

    if (ws_size >= 60 * MB + 8192) {
        // FP16 path: xh 32MB | W't 8MB | Wct 8MB | Wvh 8MB
        f16* xh   = (f16*)(ws + 8192);
        f16* Wpt  = (f16*)(ws + 8192 + 32 * MB);
        f16* Wct  = (f16*)(ws + 8192 + 40 * MB);
        f16* Wvh  = (f16*)(ws + 8192 + 48 * MB);

        cast16<<<2048, 256, 0, stream>>>(x, xh, MR * ED / 8);
        transpose_f16<<<dim3(64, 64), 256, 0, stream>>>(Wc, Wct, ED);
        cast16<<<1024, 256, 0, stream>>>(Wv, Wvh, ED * ED / 8);
        // W'^T[n][kx] = sum_j Wct[n][j] * Wv[kx][j]
        gemmW16<<<dim3(16, 16), 256, 0, stream>>>(Wct, Wvh, Wpt, ED, ED);
        // out = x @ W' + bp
        gemm256f<<<dim3(MR / 256, ED / 256), 512, 0, stream>>>(
            xh, Wpt, out, bp, ED, ED);
    } else {
        // MINIMAL fallback (~32MB): 3-term bf16 split, round-3 structure
        float* Wctf = (float*)(ws + 8192);
        u16* Wpt_hi = (u16*)(ws + 8192 + 16 * MB);
        u16* Wpt_lo = (u16*)(ws + 8192 + 24 * MB);

        transpose_f32<<<dim3(64, 64), 256, 0, stream>>>(Wc, Wctf, ED);
        gemm3<1, 0, 0><<<dim3(16, 16), 256, 0, stream>>>(
            Wctf, nullptr, nullptr, Wv, nullptr, nullptr,
            nullptr, nullptr, Wpt_hi, Wpt_lo, ED, ED, ED);
        gemm3<0, 0, 1><<<dim3(64, 16), 256, 0, stream>>>(
            x, nullptr, nullptr, nullptr, Wpt_hi, Wpt_lo,
            out, bp, nullptr, nullptr, ED, ED, ED);
    }
}

// Round 7
// 367.891 us; speedup vs baseline: 1.5165x; 1.0278x over previous
//
#include <hip/hip_runtime.h>

#define ED 2048
#define MR 8192

typedef unsigned short u16;
typedef _Float16 f16;
typedef __attribute__((ext_vector_type(8))) __bf16 bf16x8;
typedef __attribute__((ext_vector_type(8))) _Float16 f16x8;
typedef __attribute__((ext_vector_type(4))) float f32x4;

__device__ __forceinline__ u16 f2bf(float f){ __bf16 h=(__bf16)f; return __builtin_bit_cast(u16,h); }
__device__ __forceinline__ float bf2f(u16 u){ __bf16 h=__builtin_bit_cast(__bf16,u); return (float)h; }

#define MFMA16 __builtin_amdgcn_mfma_f32_16x16x32_f16
#define MFMAB  __builtin_amdgcn_mfma_f32_16x16x32_bf16

// async global->LDS, 16B per lane; LDS dest is wave-uniform base + lane*16
#define LDSLOAD(gp, lp) __builtin_amdgcn_global_load_lds( \
    (const __attribute__((address_space(1))) unsigned int*)(gp), \
    (__attribute__((address_space(3))) unsigned int*)(lp), 16, 0, 0)

// ---------------------------------------------------------------------------
// cast fp32 -> fp16 (8 elems/thread, 16B stores, grid-stride)
// ---------------------------------------------------------------------------
__global__ void cast16(const float* __restrict__ in, f16* __restrict__ out, int n8) {
    int i = blockIdx.x * 256 + threadIdx.x;
    const int stride = gridDim.x * 256;
    for (; i < n8; i += stride) {
        float4 a = reinterpret_cast<const float4*>(in)[2 * i];
        float4 b = reinterpret_cast<const float4*>(in)[2 * i + 1];
        f16x8 v;
        v[0] = (f16)a.x; v[1] = (f16)a.y; v[2] = (f16)a.z; v[3] = (f16)a.w;
        v[4] = (f16)b.x; v[5] = (f16)b.y; v[6] = (f16)b.z; v[7] = (f16)b.w;
        *reinterpret_cast<f16x8*>(out + (size_t)i * 8) = v;
    }
}

// ---------------------------------------------------------------------------
// 32x32 tiled transpose fp32 -> fp16
// ---------------------------------------------------------------------------
__global__ void transpose_f16(const float* __restrict__ in, f16* __restrict__ out, int n) {
    __shared__ float tile[32][33];
    const int bx = blockIdx.x * 32, by = blockIdx.y * 32;
    const int tx = threadIdx.x & 31, ty = threadIdx.x >> 5;
    #pragma unroll
    for (int r = ty; r < 32; r += 8)
        tile[r][tx] = in[(size_t)(by + r) * n + bx + tx];
    __syncthreads();
    #pragma unroll
    for (int r = ty; r < 32; r += 8)
        out[(size_t)(bx + r) * n + by + tx] = (f16)tile[tx][r];
}

// ---------------------------------------------------------------------------
// 32x32 tiled transpose fp32 -> fp32 (fallback path)
// ---------------------------------------------------------------------------
__global__ void transpose_f32(const float* __restrict__ in, float* __restrict__ out, int n) {
    __shared__ float tile[32][33];
    const int bx = blockIdx.x * 32, by = blockIdx.y * 32;
    const int tx = threadIdx.x & 31, ty = threadIdx.x >> 5;
    #pragma unroll
    for (int r = ty; r < 32; r += 8)
        tile[r][tx] = in[(size_t)(by + r) * n + bx + tx];
    __syncthreads();
    #pragma unroll
    for (int r = ty; r < 32; r += 8)
        out[(size_t)(bx + r) * n + by + tx] = tile[tx][r];
}

// ---------------------------------------------------------------------------
// bp[n] += (bc[n] if first chunk) + sum_{j chunk of 64} bv[j]*Wc[j][n]
// ---------------------------------------------------------------------------
__global__ void bias_kernel(const float* __restrict__ bv, const float* __restrict__ Wc,
                            const float* __restrict__ bc, float* __restrict__ bp) {
    const int n = blockIdx.x * 256 + threadIdx.x;
    const int j0 = blockIdx.y * 64;
    float s = (blockIdx.y == 0) ? bc[n] : 0.0f;
    #pragma unroll 4
    for (int j = 0; j < 64; ++j)
        s += bv[j0 + j] * Wc[(size_t)(j0 + j) * ED + n];
    atomicAdd(&bp[n], s);
}

// ===========================================================================
// MAIN GEMM (fp16): 256x256, BK=32, 8 waves (2x4), PIPE=4 LDS slots (128KB),
// 3-deep counted-vmcnt prefetch: issue STAGE(t+3), wait vmcnt(12) (= stage t
// landed, t+1..t+3 in flight; ~1500cy lead > 900cy HBM latency).
// LDS slot-major per plane (256x32 f16): elem (r,k) at (k>>3)*2048 + r*8 + (k&7).
// Staging call c in [0,16): k-slot c>>2, rows (c&3)*64+lane, LDS base c*512;
// wave w issues calls 2w, 2w+1 per plane.
// ===========================================================================
__global__ __launch_bounds__(512, 1)
void gemm256f(const f16* __restrict__ A, const f16* __restrict__ B,
              float* __restrict__ Cout, const float* __restrict__ bias,
              int Kd, int Nd)
{
    __shared__ __align__(16) f16 sA[4][8192];
    __shared__ __align__(16) f16 sB[4][8192];

    const int tid = threadIdx.x, lane = tid & 63, wave = tid >> 6;
    const int wm = wave >> 2, wn = wave & 3;          // 2 x 4 wave grid
    const int lrow = lane & 15, kq = lane >> 4;

    // XCD-chunked bijective swizzle (nwg = 256, %8 == 0)
    const int nwg = gridDim.x * gridDim.y;
    const int lin = blockIdx.y * gridDim.x + blockIdx.x;
    const int lin2 = (lin & 7) * (nwg >> 3) + (lin >> 3);
    const int bx = lin2 % gridDim.x, by = lin2 / gridDim.x;
    const long m0 = (long)bx * 256;
    const long n0 = (long)by * 256;

    const int c0 = wave * 2, c1 = c0 + 1;
    const int lb0 = c0 * 512, lb1 = c1 * 512;
    const long ga0 = (m0 + (c0 & 3) * 64 + lane) * (long)Kd + (c0 >> 2) * 8;
    const long ga1 = (m0 + (c1 & 3) * 64 + lane) * (long)Kd + (c1 >> 2) * 8;
    const long gb0 = (n0 + (c0 & 3) * 64 + lane) * (long)Kd + (c0 >> 2) * 8;
    const long gb1 = (n0 + (c1 & 3) * 64 + lane) * (long)Kd + (c1 >> 2) * 8;

    f32x4 acc[8][4];
    #pragma unroll
    for (int i = 0; i < 8; ++i)
        #pragma unroll
        for (int j = 0; j < 4; ++j)
            acc[i][j] = (f32x4){0.f, 0.f, 0.f, 0.f};

#define STAGE(buf, kt) do { \
    LDSLOAD(A + ga0 + (kt), &sA[buf][lb0]); \
    LDSLOAD(A + ga1 + (kt), &sA[buf][lb1]); \
    LDSLOAD(B + gb0 + (kt), &sB[buf][lb0]); \
    LDSLOAD(B + gb1 + (kt), &sB[buf][lb1]); \
} while (0)

    const int NT = Kd >> 5;   // 64
    STAGE(0, 0);
    STAGE(1, 32);
    STAGE(2, 64);

    for (int t = 0; t < NT; ++t) {
        const int cur = t & 3;
        // slot (t+3)&3 was last read at iter t-1; end-of-iter barrier guards it
        if (t + 3 < NT) {
            STAGE((t + 3) & 3, (t + 3) << 5);
            asm volatile("s_waitcnt vmcnt(12)" ::: "memory");  // stage t landed
        } else if (t + 2 < NT) {
            asm volatile("s_waitcnt vmcnt(8)" ::: "memory");
        } else if (t + 1 < NT) {
            asm volatile("s_waitcnt vmcnt(4)" ::: "memory");
        } else {
            asm volatile("s_waitcnt vmcnt(0)" ::: "memory");
        }
        __builtin_amdgcn_s_barrier();       // buf[cur] ready on all waves
        __builtin_amdgcn_sched_barrier(0);

        f16x8 bf[4];
        #pragma unroll
        for (int fn = 0; fn < 4; ++fn) {
            int off = kq * 2048 + (wn * 64 + fn * 16 + lrow) * 8;
            bf[fn] = *reinterpret_cast<const f16x8*>(&sB[cur][off]);
        }
        #pragma unroll
        for (int fm = 0; fm < 8; ++fm) {
            int off = kq * 2048 + (wm * 128 + fm * 16 + lrow) * 8;
            f16x8 af = *reinterpret_cast<const f16x8*>(&sA[cur][off]);
            #pragma unroll
            for (int fn = 0; fn < 4; ++fn)
                acc[fm][fn] = MFMA16(af, bf[fn], acc[fm][fn], 0, 0, 0);
        }

        __builtin_amdgcn_sched_barrier(0);
        __builtin_amdgcn_s_barrier();       // all waves done reading buf[cur]
    }
#undef STAGE

    // epilogue: C/D layout col=lane&15, row=(lane>>4)*4+i (m89-verified, dtype-indep)
    #pragma unroll
    for (int fm = 0; fm < 8; ++fm) {
        long gmb = m0 + wm * 128 + fm * 16 + kq * 4;
        #pragma unroll
        for (int fn = 0; fn < 4; ++fn) {
            long gn = n0 + wn * 64 + fn * 16 + lrow;
            float bb = bias[gn];
            #pragma unroll
            for (int i = 0; i < 4; ++i)
                Cout[(gmb + i) * Nd + gn] = acc[fm][fn][i] + bb;
        }
    }
}

// ===========================================================================
// W' GEMM (fp16): 128x128 tile, 8 waves (2x4, 2 waves/SIMD), PIPE=4 (64KB),
// 3-deep counted vmcnt. C[m][n] = A[m][K]*B[K][n], B transposed [n][K]; fp16 C.
// Plane 128x32 f16 slot-major; staging call c in [0,8): slot c>>1, half c&1;
// wave w issues call w per plane (1+1 loads/stage) -> vmcnt(6) steady.
// ===========================================================================
__global__ __launch_bounds__(512, 1)
void gemmW16(const f16* __restrict__ A, const f16* __restrict__ B,
             f16* __restrict__ Cout, int Kd, int Nd)
{
    __shared__ __align__(16) f16 sA[4][4096];
    __shared__ __align__(16) f16 sB[4][4096];

    const int tid = threadIdx.x, lane = tid & 63, wave = tid >> 6;
    const int wm = wave >> 2, wn = wave & 3;          // 2 x 4 wave grid
    const int lrow = lane & 15, kq = lane >> 4;

    const int nwg = gridDim.x * gridDim.y;
    const int lin = blockIdx.y * gridDim.x + blockIdx.x;
    const int lin2 = (lin & 7) * (nwg >> 3) + (lin >> 3);
    const int bx = lin2 % gridDim.x, by = lin2 / gridDim.x;
    const long m0 = (long)bx * 128;
    const long n0 = (long)by * 128;

    const int lb = (wave >> 1) * 1024 + (wave & 1) * 512;
    const long ga = (m0 + (wave & 1) * 64 + lane) * (long)Kd + (wave >> 1) * 8;
    const long gb = (n0 + (wave & 1) * 64 + lane) * (long)Kd + (wave >> 1) * 8;

    f32x4 acc[4][2];
    #pragma unroll
    for (int i = 0; i < 4; ++i)
        #pragma unroll
        for (int j = 0; j < 2; ++j)
            acc[i][j] = (f32x4){0.f, 0.f, 0.f, 0.f};

#define STAGEW(buf, kt) do { \
    LDSLOAD(A + ga + (kt), &sA[buf][lb]); \
    LDSLOAD(B + gb + (kt), &sB[buf][lb]); \
} while (0)

    const int NT = Kd >> 5;
    STAGEW(0, 0);
    STAGEW(1, 32);
    STAGEW(2, 64);

    for (int t = 0; t < NT; ++t) {
        const int cur = t & 3;
        if (t + 3 < NT) {
            STAGEW((t + 3) & 3, (t + 3) << 5);
            asm volatile("s_waitcnt vmcnt(6)" ::: "memory");
        } else if (t + 2 < NT) {
            asm volatile("s_waitcnt vmcnt(4)" ::: "memory");
        } else if (t + 1 < NT) {
            asm volatile("s_waitcnt vmcnt(2)" ::: "memory");
        } else {
            asm volatile("s_waitcnt vmcnt(0)" ::: "memory");
        }
        __builtin_amdgcn_s_barrier();
        __builtin_amdgcn_sched_barrier(0);

        f16x8 bf[2];
        #pragma unroll
        for (int fn = 0; fn < 2; ++fn) {
            int off = kq * 1024 + (wn * 32 + fn * 16 + lrow) * 8;
            bf[fn] = *reinterpret_cast<const f16x8*>(&sB[cur][off]);
        }
        #pragma unroll
        for (int fm = 0; fm < 4; ++fm) {
            int off = kq * 1024 + (wm * 64 + fm * 16 + lrow) * 8;
            f16x8 af = *reinterpret_cast<const f16x8*>(&sA[cur][off]);
            #pragma unroll
            for (int fn = 0; fn < 2; ++fn)
                acc[fm][fn] = MFMA16(af, bf[fn], acc[fm][fn], 0, 0, 0);
        }

        __builtin_amdgcn_sched_barrier(0);
        __builtin_amdgcn_s_barrier();
    }
#undef STAGEW

    #pragma unroll
    for (int fm = 0; fm < 4; ++fm) {
        long gmb = m0 + wm * 64 + fm * 16 + kq * 4;
        #pragma unroll
        for (int fn = 0; fn < 2; ++fn) {
            long gn = n0 + wn * 32 + fn * 16 + lrow;
            #pragma unroll
            for (int i = 0; i < 4; ++i)
                Cout[(gmb + i) * Nd + gn] = (f16)acc[fm][fn][i];
        }
    }
}

// ---------------------------------------------------------------------------
// 128x128 3-term bf16-split GEMM — MINIMAL fallback path only (round-3 code).
// ---------------------------------------------------------------------------
template<int EPIL, int APRE, int BPRE>
__global__ __launch_bounds__(256)
void gemm3(const float* __restrict__ Af, const u16* __restrict__ Ahi, const u16* __restrict__ Alo,
           const float* __restrict__ Btf, const u16* __restrict__ Bhi, const u16* __restrict__ Blo,
           float* __restrict__ Cout, const float* __restrict__ bias,
           u16* __restrict__ Ohi, u16* __restrict__ Olo, int Kd, int Ld, int Nd)
{
    __shared__ __align__(16) u16 sAhi[4096];
    __shared__ __align__(16) u16 sAlo[4096];
    __shared__ __align__(16) u16 sBhi[4096];
    __shared__ __align__(16) u16 sBlo[4096];

    const int tid = threadIdx.x, lane = tid & 63, wave = tid >> 6;
    const int wm = wave >> 1, wn = wave & 1;
    const int lrow = lane & 15, kq = lane >> 4;

    const int nwg = gridDim.x * gridDim.y;
    const int lin = blockIdx.y * gridDim.x + blockIdx.x;
    const int lin2 = (lin & 7) * (nwg >> 3) + (lin >> 3);
    const int bx = lin2 % gridDim.x, by = lin2 / gridDim.x;
    const long m0 = (long)bx * 128;
    const long n0 = (long)by * 128;
    const long koff = (long)blockIdx.z * Kd;
    if (EPIL == 2) Cout += (size_t)blockIdx.z * (size_t)gridDim.x * 128 * Nd;

    const int idx0 = wave * 2, idx1 = wave * 2 + 1;
    const int s0 = idx0 & 3, h0 = idx0 >> 2;
    const int s1 = idx1 & 3, h1 = idx1 >> 2;
    const int cb0 = s0 * 1024 + h0 * 512;
    const int cb1 = s1 * 1024 + h1 * 512;
    const long ga0 = (m0 + h0 * 64 + lane) * (long)Ld + koff + s0 * 8;
    const long ga1 = (m0 + h1 * 64 + lane) * (long)Ld + koff + s1 * 8;
    const long gb0 = (n0 + h0 * 64 + lane) * (long)Ld + koff + s0 * 8;
    const long gb1 = (n0 + h1 * 64 + lane) * (long)Ld + koff + s1 * 8;

    f32x4 acc[4][4];
    #pragma unroll
    for (int i = 0; i < 4; ++i)
        #pragma unroll
        for (int j = 0; j < 4; ++j)
            acc[i][j] = (f32x4){0.f, 0.f, 0.f, 0.f};

    float4 av[4], bvv[4];
    if (!APRE) {
        #pragma unroll
        for (int i = 0; i < 4; ++i) {
            int ch = tid + i * 256, r = ch >> 3, c4 = ch & 7;
            av[i] = *reinterpret_cast<const float4*>(Af + (m0 + r) * (long)Ld + koff + c4 * 4);
        }
    }
    if (!BPRE) {
        #pragma unroll
        for (int i = 0; i < 4; ++i) {
            int ch = tid + i * 256, r = ch >> 3, c4 = ch & 7;
            bvv[i] = *reinterpret_cast<const float4*>(Btf + (n0 + r) * (long)Ld + koff + c4 * 4);
        }
    }

    for (int kt = 0; kt < Kd; kt += 32) {
        if (APRE) {
            LDSLOAD(Ahi + ga0 + kt, sAhi + cb0);
            LDSLOAD(Ahi + ga1 + kt, sAhi + cb1);
            LDSLOAD(Alo + ga0 + kt, sAlo + cb0);
            LDSLOAD(Alo + ga1 + kt, sAlo + cb1);
        } else {
            #pragma unroll
            for (int i = 0; i < 4; ++i) {
                int ch = tid + i * 256, r = ch >> 3, c4 = ch & 7;
                int off = (c4 >> 1) * 1024 + r * 8 + (c4 & 1) * 4;
                ushort4 h, l;
                h.x = f2bf(av[i].x); l.x = f2bf(av[i].x - bf2f(h.x));
                h.y = f2bf(av[i].y); l.y = f2bf(av[i].y - bf2f(h.y));
                h.z = f2bf(av[i].z); l.z = f2bf(av[i].z - bf2f(h.z));
                h.w = f2bf(av[i].w); l.w = f2bf(av[i].w - bf2f(h.w));
                *reinterpret_cast<ushort4*>(&sAhi[off]) = h;
                *reinterpret_cast<ushort4*>(&sAlo[off]) = l;
            }
        }
        if (BPRE) {
            LDSLOAD(Bhi + gb0 + kt, sBhi + cb0);
            LDSLOAD(Bhi + gb1 + kt, sBhi + cb1);
            LDSLOAD(Blo + gb0 + kt, sBlo + cb0);
            LDSLOAD(Blo + gb1 + kt, sBlo + cb1);
        } else {
            #pragma unroll
            for (int i = 0; i < 4; ++i) {
                int ch = tid + i * 256, r = ch >> 3, c4 = ch & 7;
                int off = (c4 >> 1) * 1024 + r * 8 + (c4 & 1) * 4;
                ushort4 h, l;
                h.x = f2bf(bvv[i].x); l.x = f2bf(bvv[i].x - bf2f(h.x));
                h.y = f2bf(bvv[i].y); l.y = f2bf(bvv[i].y - bf2f(h.y));
                h.z = f2bf(bvv[i].z); l.z = f2bf(bvv[i].z - bf2f(h.z));
                h.w = f2bf(bvv[i].w); l.w = f2bf(bvv[i].w - bf2f(h.w));
                *reinterpret_cast<ushort4*>(&sBhi[off]) = h;
                *reinterpret_cast<ushort4*>(&sBlo[off]) = l;
            }
        }

        __syncthreads();

        if (!APRE && kt + 32 < Kd) {
            #pragma unroll
            for (int i = 0; i < 4; ++i) {
                int ch = tid + i * 256, r = ch >> 3, c4 = ch & 7;
                av[i] = *reinterpret_cast<const float4*>(Af + (m0 + r) * (long)Ld + koff + kt + 32 + c4 * 4);
            }
        }
        if (!BPRE && kt + 32 < Kd) {
            #pragma unroll
            for (int i = 0; i < 4; ++i) {
                int ch = tid + i * 256, r = ch >> 3, c4 = ch & 7;
                bvv[i] = *reinterpret_cast<const float4*>(Btf + (n0 + r) * (long)Ld + koff + kt + 32 + c4 * 4);
            }
        }

        bf16x8 bh[4], bl[4];
        #pragma unroll
        for (int fn = 0; fn < 4; ++fn) {
            int r = wn * 64 + fn * 16 + lrow;
            bh[fn] = *reinterpret_cast<const bf16x8*>(&sBhi[kq * 1024 + r * 8]);
            bl[fn] = *reinterpret_cast<const bf16x8*>(&sBlo[kq * 1024 + r * 8]);
        }
        #pragma unroll
        for (int fm = 0; fm < 4; ++fm) {
            int r = wm * 64 + fm * 16 + lrow;
            bf16x8 ah = *reinterpret_cast<const bf16x8*>(&sAhi[kq * 1024 + r * 8]);
            bf16x8 al = *reinterpret_cast<const bf16x8*>(&sAlo[kq * 1024 + r * 8]);
            #pragma unroll
            for (int fn = 0; fn < 4; ++fn) {
                acc[fm][fn] = MFMAB(ah, bh[fn], acc[fm][fn], 0, 0, 0);
                acc[fm][fn] = MFMAB(ah, bl[fn], acc[fm][fn], 0, 0, 0);
                acc[fm][fn] = MFMAB(al, bh[fn], acc[fm][fn], 0, 0, 0);
            }
        }

        __syncthreads();
    }

    #pragma unroll
    for (int fm = 0; fm < 4; ++fm) {
        long gmb = m0 + wm * 64 + fm * 16 + kq * 4;
        #pragma unroll
        for (int fn = 0; fn < 4; ++fn) {
            long gn = n0 + wn * 64 + fn * 16 + lrow;
            float bb = (EPIL == 0) ? bias[gn] : 0.0f;
            #pragma unroll
            for (int i = 0; i < 4; ++i) {
                float w = acc[fm][fn][i];
                if (EPIL == 0) {
                    Cout[(gmb + i) * Nd + gn] = w + bb;
                } else if (EPIL == 2) {
                    Cout[(gmb + i) * Nd + gn] = w;
                } else {
                    u16 h = f2bf(w);
                    Ohi[(gmb + i) * Nd + gn] = h;
                    Olo[(gmb + i) * Nd + gn] = f2bf(w - bf2f(h));
                }
            }
        }
    }
}

// ---------------------------------------------------------------------------
// out = x @ (Wv @ Wc) + (bv @ Wc + bc)
//   (attention collapses: einsum sums att over j; softmax rows sum to 1 -> y == v)
// ---------------------------------------------------------------------------
extern "C" void kernel_launch(void* const* d_in, const int* in_sizes, int n_in,
                              void* d_out, int out_size, void* d_ws, size_t ws_size,
                              hipStream_t stream) {
    const float* x  = (const float*)d_in[0];
    const float* Wv = (const float*)d_in[5];
    const float* bv = (const float*)d_in[6];
    const float* Wc = (const float*)d_in[7];
    const float* bc = (const float*)d_in[8];
    float* out = (float*)d_out;

    char* ws = (char*)d_ws;
    const size_t MB = 1024 * 1024;

    float* bp = (float*)ws;                 // 8KB reserved
    hipMemsetAsync(bp, 0, ED * sizeof(float), stream);
    bias_kernel<<<dim3(ED / 256, ED / 64), 256, 0, stream>>>(bv, Wc, bc, bp);

    if (ws_size >= 60 * MB + 8192) {
        // FP16 path: xh 32MB | W't 8MB | Wct 8MB | Wvh 8MB
        f16* xh   = (f16*)(ws + 8192);
        f16* Wpt  = (f16*)(ws + 8192 + 32 * MB);
        f16* Wct  = (f16*)(ws + 8192 + 40 * MB);
        f16* Wvh  = (f16*)(ws + 8192 + 48 * MB);

        cast16<<<2048, 256, 0, stream>>>(x, xh, MR * ED / 8);
        transpose_f16<<<dim3(64, 64), 256, 0, stream>>>(Wc, Wct, ED);
        cast16<<<1024, 256, 0, stream>>>(Wv, Wvh, ED * ED / 8);
        // W'^T[n][kx] = sum_j Wct[n][j] * Wv[kx][j]
        gemmW16<<<dim3(16, 16), 512, 0, stream>>>(Wct, Wvh, Wpt, ED, ED);
        // out = x @ W' + bp
        gemm256f<<<dim3(MR / 256, ED / 256), 512, 0, stream>>>(
            xh, Wpt, out, bp, ED, ED);
    } else {
        // MINIMAL fallback (~32MB): 3-term bf16 split, round-3 structure
        float* Wctf = (float*)(ws + 8192);
        u16* Wpt_hi = (u16*)(ws + 8192 + 16 * MB);
        u16* Wpt_lo = (u16*)(ws + 8192 + 24 * MB);

        transpose_f32<<<dim3(64, 64), 256, 0, stream>>>(Wc, Wctf, ED);
        gemm3<1, 0, 0><<<dim3(16, 16), 256, 0, stream>>>(
            Wctf, nullptr, nullptr, Wv, nullptr, nullptr,
            nullptr, nullptr, Wpt_hi, Wpt_lo, ED, ED, ED);
        gemm3<0, 0, 1><<<dim3(64, 16), 256, 0, stream>>>(
            x, nullptr, nullptr, nullptr, Wpt_hi, Wpt_lo,
            out, bp, nullptr, nullptr, ED, ED, ED);
    }
}